// Round 1
// baseline (163.750 us; speedup 1.0000x reference)
//
#include <hip/hip_runtime.h>

// HBilinearUpsample: Poincare-ball geodesic-midpoint 2x upsample.
// midpoint(x,y) = A*x + B*y with A,B from (|x|^2,|y|^2,x.y) only; the
// center of a 2x2 cell is midpoint(midpoint(x00,x10), midpoint(x01,x11)),
// still a linear combo of the 4 corners via the 4x4 Gram matrix.
// Edge replication == clamped neighbor index (midpoint(x,x)=x).
//
// R1 change vs 167us baseline: the old kernel ran 1024 blocks x 2 waves
// (8 waves/CU) with a 64-channel serial strided reduction per thread ->
// latency-bound at ~19% of HBM BW. Now: 4 channel-group waves per block
// cooperate (16 channels each), partial Grams combined via LDS (stride 13,
// conflict-free), 2048 blocks x 4 waves = 32 waves/CU, plus a bijective
// XCD swizzle that gives each XCD one full batch image (4 MB = its L2).

#define EPSF   1e-15f
#define MAXAT  0.99999f

__device__ __forceinline__ void midcoef(float x2, float y2, float xy,
                                        float& A, float& B) {
    float alpha  = 1.0f - 2.0f * xy + y2;
    float beta   = 1.0f - x2;
    float den_w  = fmaxf(1.0f - 2.0f * xy + x2 * y2, EPSF);
    float inv_dw = 1.0f / den_w;
    // dot(x, w)
    float dxw = (beta * xy - alpha * x2) * inv_dw;
    // |w|^2
    float wn2 = (alpha * alpha * x2 - 2.0f * alpha * beta * xy + beta * beta * y2)
                * inv_dw * inv_dw;
    wn2 = fmaxf(wn2, EPSF);
    float wn = sqrtf(wn2);
    float a  = fminf(wn, MAXAT);
    float s  = a / (1.0f + sqrtf(fmaxf(1.0f - a * a, 0.0f)));  // tanh(atanh(a)/2)
    float t  = s / wn;                 // second = t * w
    float xs = t * dxw;                // dot(x, second)
    float s2 = t * t * wn2;            // |second|^2
    float den     = fmaxf(1.0f + 2.0f * xs + x2 * s2, EPSF);
    float inv_den = 1.0f / den;
    float k = beta * t * inv_dw;
    A = ((1.0f + 2.0f * xs + s2) - k * alpha) * inv_den;
    B = (k * beta) * inv_den;
}

constexpr int Bn = 8, Cn = 64, Hn = 128, Wn = 128;
constexpr int CS  = Hn * Wn;       // channel stride (elems)
constexpr int CG  = 4;             // channel-group waves per block
constexpr int CPG = Cn / CG;       // 16 channels per group
constexpr int WT  = 64;            // w-positions per block (one wave wide)
constexpr int PAD = 13;            // LDS row stride in floats (odd -> conflict-free)

__global__ __launch_bounds__(WT * CG, 8)
void hupsample_kernel(const float* __restrict__ x, float* __restrict__ out) {
    // ---- bijective XCD swizzle: 2048 blocks = 8 XCDs x 256; each XCD gets
    // one full batch image (bx,h contiguous), so row-sharing between
    // adjacent h-blocks stays in one L2. ----
    const int lin = blockIdx.x;                 // 0..2047
    const int swz = (lin & 7) * 256 + (lin >> 3);
    const int bx  = swz & 1;                    // w-half
    const int h   = (swz >> 1) & (Hn - 1);      // 0..127
    const int b   = swz >> 8;                   // 0..7

    const int tid = threadIdx.x;
    const int wl  = tid & (WT - 1);             // 0..63
    const int cg  = tid >> 6;                   // 0..3 (one wave each)
    const int w   = bx * WT + wl;               // 0..127
    const int wp  = (w + 1 < Wn) ? (w + 1) : (Wn - 1);
    const int hp  = (h + 1 < Hn) ? (h + 1) : (Hn - 1);

    const float* xb  = x + (size_t)b * Cn * CS + (size_t)cg * CPG * CS;
    const float* p00 = xb + h  * Wn + w;
    const float* p10 = xb + h  * Wn + wp;
    const float* p01 = xb + hp * Wn + w;
    const float* p11 = xb + hp * Wn + wp;

    // ---- pass 1: partial Gram over this group's 16 channels ----
    float g00 = 0.f, g10 = 0.f, g01 = 0.f, g11 = 0.f;
    float d0010 = 0.f, d0111 = 0.f, d0001 = 0.f;
    float d0011 = 0.f, d1001 = 0.f, d1011 = 0.f;
#pragma unroll 4
    for (int c = 0; c < CPG; ++c) {
        float v00 = p00[c * CS];
        float v10 = p10[c * CS];
        float v01 = p01[c * CS];
        float v11 = p11[c * CS];
        g00   += v00 * v00;  g10   += v10 * v10;
        g01   += v01 * v01;  g11   += v11 * v11;
        d0010 += v00 * v10;  d0111 += v01 * v11;
        d0001 += v00 * v01;  d0011 += v00 * v11;
        d1001 += v10 * v01;  d1011 += v10 * v11;
    }

    // ---- combine the 4 group-partials through LDS ----
    __shared__ float sums[CG * WT * PAD];       // 13.3 KB
    {
        float* my = &sums[(cg * WT + wl) * PAD];
        my[0] = g00;   my[1] = g10;   my[2] = g01;   my[3] = g11;
        my[4] = d0010; my[5] = d0111; my[6] = d0001; my[7] = d0011;
        my[8] = d1001; my[9] = d1011;
    }
    __syncthreads();
    {
        const float* r0 = &sums[(0 * WT + wl) * PAD];
        const float* r1 = &sums[(1 * WT + wl) * PAD];
        const float* r2 = &sums[(2 * WT + wl) * PAD];
        const float* r3 = &sums[(3 * WT + wl) * PAD];
        g00   = r0[0] + r1[0] + r2[0] + r3[0];
        g10   = r0[1] + r1[1] + r2[1] + r3[1];
        g01   = r0[2] + r1[2] + r2[2] + r3[2];
        g11   = r0[3] + r1[3] + r2[3] + r3[3];
        d0010 = r0[4] + r1[4] + r2[4] + r3[4];
        d0111 = r0[5] + r1[5] + r2[5] + r3[5];
        d0001 = r0[6] + r1[6] + r2[6] + r3[6];
        d0011 = r0[7] + r1[7] + r2[7] + r3[7];
        d1001 = r0[8] + r1[8] + r2[8] + r3[8];
        d1011 = r0[9] + r1[9] + r2[9] + r3[9];
    }

    // ---- scalar coefficients (computed redundantly per group: trivial) ----
    float Ah, Bh;  midcoef(g00, g10, d0010, Ah, Bh);   // horizontal mid, row h
    float A2, B2;  midcoef(g01, g11, d0111, A2, B2);   // horizontal mid, row h+1
    float Av, Bv;  midcoef(g00, g01, d0001, Av, Bv);   // vertical mid

    float a2 = Ah * Ah * g00 + 2.0f * Ah * Bh * d0010 + Bh * Bh * g10;
    float b2 = A2 * A2 * g01 + 2.0f * A2 * B2 * d0111 + B2 * B2 * g11;
    float ab = Ah * A2 * d0001 + Ah * B2 * d0011 + Bh * A2 * d1001 + Bh * B2 * d1011;
    float A3, B3;  midcoef(a2, b2, ab, A3, B3);
    float CA = A3 * Ah, CB = A3 * Bh, CC = B3 * A2, CD = B3 * B2;

    // ---- pass 2: emit this group's 16 channels (reloads are L1/L2-hot) ----
    float* ob = out + (size_t)b * Cn * (4 * CS) + (size_t)cg * CPG * (4 * CS);
    const size_t rbase = (size_t)(2 * h) * (2 * Wn) + (size_t)(2 * w);
#pragma unroll 4
    for (int c = 0; c < CPG; ++c) {
        float v00 = p00[c * CS];
        float v10 = p10[c * CS];
        float v01 = p01[c * CS];
        float v11 = p11[c * CS];
        float oh = Ah * v00 + Bh * v10;
        float ov = Av * v00 + Bv * v01;
        float oc = CA * v00 + CB * v10 + CC * v01 + CD * v11;
        size_t base = (size_t)c * (4 * CS) + rbase;
        *(float2*)(ob + base)               = make_float2(v00, oh);
        *(float2*)(ob + base + 2 * Wn)      = make_float2(ov, oc);
    }
}

extern "C" void kernel_launch(void* const* d_in, const int* in_sizes, int n_in,
                              void* d_out, int out_size, void* d_ws, size_t ws_size,
                              hipStream_t stream) {
    const float* x = (const float*)d_in[0];
    float* out = (float*)d_out;
    hipLaunchKernelGGL(hupsample_kernel, dim3(2048), dim3(256), 0, stream, x, out);
}